// Round 4
// baseline (635.544 us; speedup 1.0000x reference)
//
#include <hip/hip_runtime.h>

#define DEV __device__ __forceinline__

typedef __attribute__((ext_vector_type(4))) float f32x4;
typedef __attribute__((ext_vector_type(4))) unsigned short u16x4;
typedef __attribute__((ext_vector_type(8))) __bf16 bf16x8;

constexpr int NB = 16, SL = 2048, EM = 1024, DKD = 128;

DEV unsigned short f2bf(float f) {           // fp32 -> bf16 RNE
  unsigned int u = __float_as_uint(f);
  u += 0x7FFFu + ((u >> 16) & 1u);
  return (unsigned short)(u >> 16);
}

DEV f32x4 mfma16(bf16x8 a, bf16x8 b, f32x4 c) {
  return __builtin_amdgcn_mfma_f32_16x16x32_bf16(a, b, c, 0, 0, 0);
}

DEV bf16x8 cvt8(f32x4 a, f32x4 b) {
  bf16x8 r;
  r[0] = (__bf16)a[0]; r[1] = (__bf16)a[1]; r[2] = (__bf16)a[2]; r[3] = (__bf16)a[3];
  r[4] = (__bf16)b[0]; r[5] = (__bf16)b[1]; r[6] = (__bf16)b[2]; r[7] = (__bf16)b[3];
  return r;
}

// ---------------------------------------------------------------------------
// prep_w: W[m] fp32 [1024][128]  ->  Wt bf16 [m][n=128][k=1024] (transposed).
// grid 48 = (m, kc64). LDS-staged transpose.
// ---------------------------------------------------------------------------
__global__ __launch_bounds__(256) void prep_w(
    const float* __restrict__ Wq, const float* __restrict__ Wk,
    const float* __restrict__ Wv, unsigned short* __restrict__ Wt)
{
  __shared__ unsigned short T[128 * 73];     // [n][kk+pad]
  const int tid = threadIdx.x;
  const int m = blockIdx.x >> 4, kc = blockIdx.x & 15;
  const float* W = (m == 0) ? Wq : ((m == 1) ? Wk : Wv);
  #pragma unroll
  for (int it = 0; it < 8; ++it) {
    int idx = it * 256 + tid;                // 2048 f32x4 chunks
    int kk = idx >> 5, n4 = (idx & 31) * 4;
    f32x4 w4 = *(const f32x4*)(W + (size_t)(kc * 64 + kk) * DKD + n4);
    #pragma unroll
    for (int j = 0; j < 4; ++j) T[(n4 + j) * 73 + kk] = f2bf(w4[j]);
  }
  __syncthreads();
  #pragma unroll
  for (int it = 0; it < 4; ++it) {
    int c = it * 256 + tid;                  // 1024 out chunks of 8 k
    int n = c >> 3, k8 = c & 7;
    unsigned short v[8];
    #pragma unroll
    for (int e = 0; e < 8; ++e) v[e] = T[n * 73 + k8 * 8 + e];
    unsigned short* o = Wt + ((size_t)(m * 128 + n) * EM) + kc * 64 + k8 * 8;
    *(u16x4*)o       = u16x4{v[0], v[1], v[2], v[3]};
    *(u16x4*)(o + 4) = u16x4{v[4], v[5], v[6], v[7]};
  }
}

// ---------------------------------------------------------------------------
// proj_qk: Q,K = ctx @ {Wq,Wk}. No LDS, no barriers. M-tile 64, N=256 (Q|K).
// B-frags direct from Wt (L1/L2-hot); A fp32 direct + in-reg cvt.
// ---------------------------------------------------------------------------
__global__ __launch_bounds__(256, 2) void proj_qk(
    const float* __restrict__ ctx, const unsigned short* __restrict__ Wt,
    const int* __restrict__ lens, unsigned short* __restrict__ Qo,
    unsigned short* __restrict__ Ko)
{
  const int tid = threadIdx.x;
  const int wave = tid >> 6, lane = tid & 63;
  const int quad = lane >> 4, mm = lane & 15;
  const int rb = blockIdx.x * 64;

  // per-lo weight row pointers (ctg<8 -> Wq row ctg*16+mm; else Wk)
  const unsigned short* wrow[4];
  #pragma unroll
  for (int lo = 0; lo < 4; ++lo) {
    int ctg = wave * 4 + lo;
    int row = (ctg < 8) ? (ctg * 16 + mm) : (128 + (ctg - 8) * 16 + mm);
    wrow[lo] = Wt + (size_t)row * EM;
  }
  const float* arow[4];
  #pragma unroll
  for (int rt = 0; rt < 4; ++rt)
    arow[rt] = ctx + (size_t)(rb + rt * 16 + mm) * EM;

  f32x4 acc[4][4];
  #pragma unroll
  for (int i = 0; i < 4; ++i)
    #pragma unroll
    for (int j = 0; j < 4; ++j) acc[i][j] = f32x4{0.f, 0.f, 0.f, 0.f};

  #pragma unroll 1
  for (int kc = 0; kc < 16; ++kc) {
    #pragma unroll
    for (int ks = 0; ks < 2; ++ks) {
      const int ko = kc * 64 + ks * 32 + quad * 8;
      bf16x8 af[4];
      #pragma unroll
      for (int rt = 0; rt < 4; ++rt) {
        const float* ap = arow[rt] + ko;
        f32x4 a0 = *(const f32x4*)ap;
        f32x4 a1 = *(const f32x4*)(ap + 4);
        af[rt] = cvt8(a0, a1);
      }
      #pragma unroll
      for (int lo = 0; lo < 4; ++lo) {
        bf16x8 bf = *(const bf16x8*)(wrow[lo] + ko);
        #pragma unroll
        for (int rt = 0; rt < 4; ++rt)
          acc[rt][lo] = mfma16(af[rt], bf, acc[rt][lo]);
      }
    }
  }
  const int len = lens[blockIdx.x >> 5];
  const float SCALE = 1.4426950408889634f * 0.08838834764831845f; // log2e/sqrt(128)
  #pragma unroll
  for (int rt = 0; rt < 4; ++rt)
    #pragma unroll
    for (int lo = 0; lo < 4; ++lo) {
      const int ctg = wave * 4 + lo;
      #pragma unroll
      for (int reg = 0; reg < 4; ++reg) {
        const int row = rb + rt * 16 + quad * 4 + reg;
        const int j = row & (SL - 1);
        const float val = acc[rt][lo][reg];
        if (ctg < 8) {
          const int d = ctg * 16 + mm;
          Qo[(size_t)row * DKD + d] = f2bf(val * ((j < len) ? SCALE : 0.f));
        } else {
          const int d = (ctg - 8) * 16 + mm;
          Ko[(size_t)row * DKD + d] = f2bf(val);
        }
      }
    }
}

// ---------------------------------------------------------------------------
// proj_v: V = x @ Wv. Same structure, N=128. Output plain transposed
// Vt[b][d][j].
// ---------------------------------------------------------------------------
__global__ __launch_bounds__(256, 2) void proj_v(
    const float* __restrict__ x, const unsigned short* __restrict__ Wt,
    unsigned short* __restrict__ Vt)
{
  const int tid = threadIdx.x;
  const int wave = tid >> 6, lane = tid & 63;
  const int quad = lane >> 4, mm = lane & 15;
  const int rb = blockIdx.x * 64;

  const unsigned short* wrow[2];
  #pragma unroll
  for (int lo = 0; lo < 2; ++lo)
    wrow[lo] = Wt + (size_t)(256 + (wave * 2 + lo) * 16 + mm) * EM;
  const float* arow[4];
  #pragma unroll
  for (int rt = 0; rt < 4; ++rt)
    arow[rt] = x + (size_t)(rb + rt * 16 + mm) * EM;

  f32x4 acc[4][2];
  #pragma unroll
  for (int i = 0; i < 4; ++i) { acc[i][0] = f32x4{0.f,0.f,0.f,0.f}; acc[i][1] = f32x4{0.f,0.f,0.f,0.f}; }

  #pragma unroll 1
  for (int kc = 0; kc < 16; ++kc) {
    #pragma unroll
    for (int ks = 0; ks < 2; ++ks) {
      const int ko = kc * 64 + ks * 32 + quad * 8;
      bf16x8 af[4];
      #pragma unroll
      for (int rt = 0; rt < 4; ++rt) {
        const float* ap = arow[rt] + ko;
        f32x4 a0 = *(const f32x4*)ap;
        f32x4 a1 = *(const f32x4*)(ap + 4);
        af[rt] = cvt8(a0, a1);
      }
      #pragma unroll
      for (int lo = 0; lo < 2; ++lo) {
        bf16x8 bf = *(const bf16x8*)(wrow[lo] + ko);
        #pragma unroll
        for (int rt = 0; rt < 4; ++rt)
          acc[rt][lo] = mfma16(af[rt], bf, acc[rt][lo]);
      }
    }
  }
  #pragma unroll
  for (int rt = 0; rt < 4; ++rt)
    #pragma unroll
    for (int lo = 0; lo < 2; ++lo) {
      const int d = (wave * 2 + lo) * 16 + mm;
      const int row0 = rb + rt * 16 + quad * 4;
      const int b = row0 >> 11, j0 = row0 & (SL - 1);
      u16x4 pk = u16x4{ f2bf(acc[rt][lo][0]), f2bf(acc[rt][lo][1]),
                        f2bf(acc[rt][lo][2]), f2bf(acc[rt][lo][3]) };
      *(u16x4*)(Vt + (size_t)b * DKD * SL + (size_t)d * SL + j0) = pk;
    }
}

// ---------------------------------------------------------------------------
// attn: flash attention, 64 q-rows/block, 32-key inner blocks, K/V fragments
// loaded DIRECTLY from global (L1/L2-hot) — no barriers in the k-loop.
// Fully-padded query blocks short-circuit to mean(V[0..len)).
// ---------------------------------------------------------------------------
__global__ __launch_bounds__(256, 3) void attn(
    const unsigned short* __restrict__ Qw, const unsigned short* __restrict__ Kw,
    const unsigned short* __restrict__ Vt, const int* __restrict__ lens,
    float* __restrict__ out)
{
  __shared__ unsigned short Ps[4][16 * 40];    // per-wave P [q][32 keys + pad8]
  __shared__ float mv[128];
  const int tid = threadIdx.x;
  const int wave = tid >> 6, lane = tid & 63;
  const int quad = lane >> 4, mm = lane & 15;
  const int b = blockIdx.y;
  const int qb = ((int)gridDim.x - 1 - (int)blockIdx.x) * 64;  // heavy blocks first
  const int len = lens[b];
  const unsigned short* vbase0 = Vt + (size_t)b * DKD * SL;

  if (qb >= len) {
    // ---- mean-V path: every row in this block averages V[0..len) ----
    const int half = tid >> 7, d = tid & 127;
    const unsigned short* vbase = vbase0 + (size_t)d * SL;
    float sum = 0.f;
    for (int j0 = half * 8; j0 < len; j0 += 16) {
      if (j0 + 8 <= len) {
        bf16x8 v = *(const bf16x8*)(vbase + j0);
        sum += (float)v[0] + (float)v[1] + (float)v[2] + (float)v[3]
             + (float)v[4] + (float)v[5] + (float)v[6] + (float)v[7];
      } else {
        for (int r = 0; r < 8; ++r)
          if (j0 + r < len) sum += (float)*(const __bf16*)(vbase + j0 + r);
      }
    }
    if (half == 0) mv[d] = sum;
    __syncthreads();
    if (half == 1) mv[d] += sum;
    __syncthreads();
    const float val = mv[d] / (float)len;
    #pragma unroll 1
    for (int it = 0; it < 32; ++it) {
      const int row = qb + half + it * 2;
      out[((size_t)b * SL + row) * DKD + d] = val;
    }
    return;
  }

  const int kend = min(qb + 64, len);
  const int irow0 = qb + wave * 16 + quad * 4;

  bf16x8 aQ[4];
  {
    const unsigned short* qbase =
        Qw + (size_t)(b * SL + qb + wave * 16 + mm) * DKD + quad * 8;
    #pragma unroll
    for (int cc = 0; cc < 4; ++cc) aQ[cc] = *(const bf16x8*)(qbase + cc * 32);
  }
  float mr[4], lr[4];
  #pragma unroll
  for (int r = 0; r < 4; ++r) { mr[r] = -__builtin_inff(); lr[r] = 0.f; }
  f32x4 acc[8];
  #pragma unroll
  for (int i = 0; i < 8; ++i) acc[i] = f32x4{0.f,0.f,0.f,0.f};

  #pragma unroll 1
  for (int kb = 0; kb < kend; kb += 32) {
    // S = Q K^T : 2 key-tiles of 16, direct global K frags
    f32x4 s2[2];
    #pragma unroll
    for (int jt = 0; jt < 2; ++jt) {
      f32x4 c = f32x4{0.f,0.f,0.f,0.f};
      const unsigned short* kr =
          Kw + (size_t)(b * SL + kb + jt * 16 + mm) * DKD + quad * 8;
      #pragma unroll
      for (int cc = 0; cc < 4; ++cc) {
        bf16x8 kf = *(const bf16x8*)(kr + cc * 32);
        c = mfma16(aQ[cc], kf, c);
      }
      s2[jt] = c;
    }

    float alpha[4];
    #pragma unroll
    for (int reg = 0; reg < 4; ++reg) {
      const int jl = min(irow0 + reg + 1, len);   // keys j < jl valid
      float v0 = (kb + mm      < jl) ? s2[0][reg] : -__builtin_inff();
      float v1 = (kb + 16 + mm < jl) ? s2[1][reg] : -__builtin_inff();
      float mx = fmaxf(v0, v1);
      #pragma unroll
      for (int xm = 1; xm < 16; xm <<= 1) mx = fmaxf(mx, __shfl_xor(mx, xm));
      const float mn = fmaxf(mr[reg], mx);
      alpha[reg] = __builtin_amdgcn_exp2f(mr[reg] - mn);
      const float p0 = __builtin_amdgcn_exp2f(v0 - mn);
      const float p1 = __builtin_amdgcn_exp2f(v1 - mn);
      float sm = p0 + p1;
      #pragma unroll
      for (int xm = 1; xm < 16; xm <<= 1) sm += __shfl_xor(sm, xm);
      lr[reg] = lr[reg] * alpha[reg] + sm;
      mr[reg] = mn;
      const int prow = quad * 4 + reg;
      Ps[wave][prow * 40 + mm]      = f2bf(p0);
      Ps[wave][prow * 40 + 16 + mm] = f2bf(p1);
    }
    #pragma unroll
    for (int nt = 0; nt < 8; ++nt) {
      f32x4 a = acc[nt];
      a[0] *= alpha[0]; a[1] *= alpha[1]; a[2] *= alpha[2]; a[3] *= alpha[3];
      acc[nt] = a;
    }
    __asm__ volatile("s_waitcnt lgkmcnt(0)" ::: "memory");  // P writes -> reads
    bf16x8 aP = *(const bf16x8*)(&Ps[wave][mm * 40 + quad * 8]);
    #pragma unroll
    for (int nt = 0; nt < 8; ++nt) {
      const unsigned short* vr = vbase0 + (size_t)(nt * 16 + mm) * SL + kb + quad * 8;
      bf16x8 vf = *(const bf16x8*)vr;
      acc[nt] = mfma16(aP, vf, acc[nt]);
    }
  }

  #pragma unroll
  for (int reg = 0; reg < 4; ++reg) {
    const float rl = 1.0f / lr[reg];
    const size_t base = ((size_t)b * SL + irow0 + reg) * DKD + mm;
    #pragma unroll
    for (int nt = 0; nt < 8; ++nt)
      out[base + nt * 16] = acc[nt][reg] * rl;
  }
}

// ---------------------------------------------------------------------------
extern "C" void kernel_launch(void* const* d_in, const int* in_sizes, int n_in,
                              void* d_out, int out_size, void* d_ws, size_t ws_size,
                              hipStream_t stream) {
  const float* x    = (const float*)d_in[0];
  const float* ctx  = (const float*)d_in[1];
  const int*   lens = (const int*)d_in[2];
  const float* Wq   = (const float*)d_in[3];
  const float* Wk   = (const float*)d_in[4];
  const float* Wv   = (const float*)d_in[5];
  float* out = (float*)d_out;

  const size_t QKV = (size_t)NB * SL * DKD * sizeof(unsigned short); // 8 MiB each
  const size_t WTSZ = (size_t)3 * 128 * EM * sizeof(unsigned short); // 768 KiB
  if (ws_size < 3 * QKV + WTSZ) return;
  unsigned short* Qws = (unsigned short*)d_ws;
  unsigned short* Kws = (unsigned short*)((char*)d_ws + QKV);
  unsigned short* Vts = (unsigned short*)((char*)d_ws + 2 * QKV);
  unsigned short* Wt  = (unsigned short*)((char*)d_ws + 3 * QKV);

  prep_w <<<dim3(48), 256, 0, stream>>>(Wq, Wk, Wv, Wt);
  proj_qk<<<dim3(NB * SL / 64), 256, 0, stream>>>(ctx, Wt, lens, Qws, Kws);
  proj_v <<<dim3(NB * SL / 64), 256, 0, stream>>>(x, Wt, Vts);
  attn   <<<dim3(SL / 64, NB), 256, 0, stream>>>(Qws, Kws, Vts, lens, out);
}